// Round 4
// baseline (359.999 us; speedup 1.0000x reference)
//
#include <hip/hip_runtime.h>
#include <hip/hip_bf16.h>
#include <stdint.h>

#define B_  32
#define T_  512
#define C_  1024
#define NH_ 16
#define DH_ 64

typedef __attribute__((ext_vector_type(8))) __bf16 bf16x8;
typedef __attribute__((ext_vector_type(4))) __bf16 bf16x4;
typedef __attribute__((ext_vector_type(4))) float  f32x4;

__device__ __forceinline__ void gload_lds16(const void* g, void* lds) {
  __builtin_amdgcn_global_load_lds(
      (const __attribute__((address_space(1))) void*)(uintptr_t)g,
      (__attribute__((address_space(3))) void*)(uint32_t)(uintptr_t)lds,
      16, 0, 0);
}

// ---------------- cast f32 -> bf16 (vectorized) ----------------
__global__ void cast_kernel(const float* __restrict__ src, __bf16* __restrict__ dst, int n4) {
  int i = blockIdx.x * blockDim.x + threadIdx.x;
  if (i >= n4) return;
  f32x4 v = *(const f32x4*)(src + i * 4);
  bf16x4 o;
  o[0] = (__bf16)v[0]; o[1] = (__bf16)v[1]; o[2] = (__bf16)v[2]; o[3] = (__bf16)v[3];
  *(bf16x4*)(dst + i * 4) = o;
}

// ---------------- rope tables (f32) ----------------
__global__ void rope_tables_kernel(float* __restrict__ cosT, float* __restrict__ sinT) {
  int i = blockIdx.x * blockDim.x + threadIdx.x;  // T_*32
  int t = i >> 5, f = i & 31;
  float inv = powf(10000.0f, -(float)(2 * f) / 64.0f);
  float fr = (float)t * inv;
  cosT[i] = cosf(fr);
  sinT[i] = sinf(fr);
}

// ---------------- rope apply to Q (with 1/8 scale) and K, in place ----------------
__global__ void rope_apply_kernel(__bf16* __restrict__ q, __bf16* __restrict__ k,
                                  const float* __restrict__ cosT, const float* __restrict__ sinT) {
  int idx = blockIdx.x * blockDim.x + threadIdx.x;  // B*NH*T*8
  int chunk = idx & 7;
  int row = idx >> 3;         // index into [B*NH*T]
  int t = row & (T_ - 1);
  int base = row * DH_ + chunk * 8;
  int ci = t * 32 + chunk * 4;
  f32x4 c = *(const f32x4*)(cosT + ci);
  f32x4 s = *(const f32x4*)(sinT + ci);
  bf16x8 qv = *(const bf16x8*)(q + base);
  bf16x8 kv = *(const bf16x8*)(k + base);
  bf16x8 qo, ko;
#pragma unroll
  for (int p = 0; p < 4; p++) {
    float q0 = (float)qv[2 * p], q1 = (float)qv[2 * p + 1];
    float k0 = (float)kv[2 * p], k1 = (float)kv[2 * p + 1];
    qo[2 * p]     = (__bf16)(0.125f * (q0 * c[p] - q1 * s[p]));
    qo[2 * p + 1] = (__bf16)(0.125f * (q0 * s[p] + q1 * c[p]));
    ko[2 * p]     = (__bf16)(k0 * c[p] - k1 * s[p]);
    ko[2 * p + 1] = (__bf16)(k0 * s[p] + k1 * c[p]);
  }
  *(bf16x8*)(q + base) = qo;
  *(bf16x8*)(k + base) = ko;
}

// ---------------- B^T GEMM: out[m,n] = sum_k A[m,k]*W[n,k] ----------------
// MODE 0: fused QKV, N=3072 (W0/W1/W2 selected by bn>>3); writes q,k [B,NH,T,DH]
//         and vt [B,NH,DH,T], all bf16.
// MODE 1: out projection, N=1024 (W0 only); writes f32 to outp.
// AF32/BF32: operand is f32 in global -> reg-staged cast + ds_write_b128
//            (global_load_lds path otherwise).
template <int MODE, bool AF32, bool BF32>
__global__ __launch_bounds__(256) void gemm_bt(
    const void* __restrict__ Av,
    const void* __restrict__ W0v, const void* __restrict__ W1v, const void* __restrict__ W2v,
    __bf16* __restrict__ q, __bf16* __restrict__ k, __bf16* __restrict__ vt,
    float* __restrict__ outp) {
  __shared__ __bf16 As[128 * 64];
  __shared__ __bf16 Bs[128 * 64];
  const int K = C_;
  int tid = threadIdx.x;
  int lane = tid & 63, wave = tid >> 6;
  int ql = lane & 15, g = lane >> 4;
  int wr = wave >> 1, wc = wave & 1;
  int bm = blockIdx.x & 127, bn = blockIdx.x >> 7;

  const void* Wsel; int bnl;
  if (MODE == 0) { Wsel = (bn < 8) ? W0v : (bn < 16) ? W1v : W2v; bnl = bn & 7; }
  else           { Wsel = W0v; bnl = bn; }

  f32x4 acc[4][4] = {};

  int srow = tid >> 3, scol = (tid & 7) * 8;
  __bf16* AsP = &As[srow * 64 + scol];
  __bf16* BsP = &Bs[srow * 64 + scol];

  const __bf16* Ab = nullptr; const float* Af = nullptr;
  if constexpr (AF32) Af = (const float*)Av + (size_t)(bm * 128 + srow) * K + scol;
  else                Ab = (const __bf16*)Av + (size_t)(bm * 128 + srow) * K + scol;
  const __bf16* Wb = nullptr; const float* Wf = nullptr;
  if constexpr (BF32) Wf = (const float*)Wsel + (size_t)(bnl * 128 + srow) * K + scol;
  else                Wb = (const __bf16*)Wsel + (size_t)(bnl * 128 + srow) * K + scol;

  for (int k0 = 0; k0 < K; k0 += 64) {
    if constexpr (AF32) {
#pragma unroll
      for (int i = 0; i < 4; i++) {
        f32x4 lo = *(const f32x4*)(Af + (size_t)i * 32 * K + k0);
        f32x4 hi = *(const f32x4*)(Af + (size_t)i * 32 * K + k0 + 4);
        bf16x8 vv;
        vv[0] = (__bf16)lo[0]; vv[1] = (__bf16)lo[1]; vv[2] = (__bf16)lo[2]; vv[3] = (__bf16)lo[3];
        vv[4] = (__bf16)hi[0]; vv[5] = (__bf16)hi[1]; vv[6] = (__bf16)hi[2]; vv[7] = (__bf16)hi[3];
        *(bf16x8*)(AsP + i * 2048) = vv;
      }
    } else {
#pragma unroll
      for (int i = 0; i < 4; i++) gload_lds16(Ab + (size_t)i * 32 * K + k0, AsP + i * 2048);
    }
    if constexpr (BF32) {
#pragma unroll
      for (int i = 0; i < 4; i++) {
        f32x4 lo = *(const f32x4*)(Wf + (size_t)i * 32 * K + k0);
        f32x4 hi = *(const f32x4*)(Wf + (size_t)i * 32 * K + k0 + 4);
        bf16x8 vv;
        vv[0] = (__bf16)lo[0]; vv[1] = (__bf16)lo[1]; vv[2] = (__bf16)lo[2]; vv[3] = (__bf16)lo[3];
        vv[4] = (__bf16)hi[0]; vv[5] = (__bf16)hi[1]; vv[6] = (__bf16)hi[2]; vv[7] = (__bf16)hi[3];
        *(bf16x8*)(BsP + i * 2048) = vv;
      }
    } else {
#pragma unroll
      for (int i = 0; i < 4; i++) gload_lds16(Wb + (size_t)i * 32 * K + k0, BsP + i * 2048);
    }
    __syncthreads();
#pragma unroll
    for (int kk = 0; kk < 2; kk++) {
      bf16x8 a[4], b[4];
#pragma unroll
      for (int m = 0; m < 4; m++)
        a[m] = *(const bf16x8*)&As[(wr * 64 + m * 16 + ql) * 64 + kk * 32 + g * 8];
#pragma unroll
      for (int n = 0; n < 4; n++)
        b[n] = *(const bf16x8*)&Bs[(wc * 64 + n * 16 + ql) * 64 + kk * 32 + g * 8];
#pragma unroll
      for (int m = 0; m < 4; m++)
#pragma unroll
        for (int n = 0; n < 4; n++)
          acc[m][n] = __builtin_amdgcn_mfma_f32_16x16x32_bf16(a[m], b[n], acc[m][n], 0, 0, 0);
    }
    __syncthreads();
  }

  int r0 = bm * 128 + wr * 64;
  int c0 = bn * 128 + wc * 64;
  if (MODE == 0) {
    int mat = c0 >> 10;  // block-uniform: 0=Q,1=K,2=V
#pragma unroll
    for (int m = 0; m < 4; m++) {
      int row = r0 + m * 16 + g * 4;
      int b = row >> 9, t = row & 511;
#pragma unroll
      for (int n = 0; n < 4; n++) {
        int col = c0 + n * 16 + ql;
        int h = (col & 1023) >> 6, d = col & 63;
        if (mat == 2) {
          bf16x4 ov;
#pragma unroll
          for (int r = 0; r < 4; r++) ov[r] = (__bf16)acc[m][n][r];
          *(bf16x4*)(vt + ((size_t)(b * NH_ + h) * DH_ + d) * T_ + t) = ov;
        } else {
          __bf16* dst = (mat == 0 ? q : k) + ((size_t)(b * NH_ + h) * T_ + t) * DH_ + d;
#pragma unroll
          for (int r = 0; r < 4; r++) dst[r * DH_] = (__bf16)acc[m][n][r];
        }
      }
    }
  } else {
#pragma unroll
    for (int m = 0; m < 4; m++) {
      int row = r0 + m * 16 + g * 4;
#pragma unroll
      for (int r = 0; r < 4; r++)
#pragma unroll
        for (int n = 0; n < 4; n++)
          outp[(size_t)(row + r) * C_ + c0 + n * 16 + ql] = acc[m][n][r];
    }
  }
}

// ---------------- flash attention, swapped-operand MFMA ----------------
// grid = B*NH*2 blocks, 256 threads (4 waves); each wave owns 64 q rows.
// S^T D-frag (row=4g+r, verified m89/m91) reused directly as PV B-fragment
// under the split-half assumed k-map mu(g,j) = 4g + (j&3) + 16*(j>>2);
// V^T (A operand) loaded with the same mu. Correct for any true HW k-map
// by bijection invariance.
__global__ __launch_bounds__(256) void attn_kernel(
    const __bf16* __restrict__ qg, const __bf16* __restrict__ kg,
    const __bf16* __restrict__ vg, __bf16* __restrict__ ao) {
  int lane = threadIdx.x & 63, wave = threadIdx.x >> 6;
  int ql = lane & 15, g = lane >> 4;
  int bh = blockIdx.x >> 1;
  int q0 = (blockIdx.x & 1) * 256 + wave * 64;
  int b = bh >> 4, h = bh & 15;
  const __bf16* qp = qg + (size_t)bh * (T_ * DH_);
  const __bf16* kp = kg + (size_t)bh * (T_ * DH_);
  const __bf16* vp = vg + (size_t)bh * (T_ * DH_);  // [DH][T]

  bf16x8 qf[4][2];
#pragma unroll
  for (int s = 0; s < 4; s++)
#pragma unroll
    for (int kk = 0; kk < 2; kk++)
      qf[s][kk] = *(const bf16x8*)(qp + (q0 + s * 16 + ql) * DH_ + kk * 32 + g * 8);

  f32x4 o[4][4] = {};  // O^T accum: rows dh=c*16+4g+r, col q=ql
  float mrow[4] = {-1e30f, -1e30f, -1e30f, -1e30f};
  float lrow[4] = {0.f, 0.f, 0.f, 0.f};

  for (int kv0 = 0; kv0 < T_; kv0 += 32) {
    bf16x8 kf[2][2], vf[4];
#pragma unroll
    for (int sub = 0; sub < 2; sub++)
#pragma unroll
      for (int kk = 0; kk < 2; kk++)
        kf[sub][kk] = *(const bf16x8*)(kp + (kv0 + sub * 16 + ql) * DH_ + kk * 32 + g * 8);
#pragma unroll
    for (int c = 0; c < 4; c++) {
      bf16x4 vlo = *(const bf16x4*)(vp + (c * 16 + ql) * T_ + kv0 + g * 4);
      bf16x4 vhi = *(const bf16x4*)(vp + (c * 16 + ql) * T_ + kv0 + 16 + g * 4);
#pragma unroll
      for (int r = 0; r < 4; r++) { vf[c][r] = vlo[r]; vf[c][4 + r] = vhi[r]; }
    }

#pragma unroll
    for (int s = 0; s < 4; s++) {
      f32x4 s0 = {0.f, 0.f, 0.f, 0.f}, s1 = {0.f, 0.f, 0.f, 0.f};
#pragma unroll
      for (int kk = 0; kk < 2; kk++) {
        s0 = __builtin_amdgcn_mfma_f32_16x16x32_bf16(kf[0][kk], qf[s][kk], s0, 0, 0, 0);
        s1 = __builtin_amdgcn_mfma_f32_16x16x32_bf16(kf[1][kk], qf[s][kk], s1, 0, 0, 0);
      }
      float tm = s0[0];
#pragma unroll
      for (int r = 1; r < 4; r++) tm = fmaxf(tm, s0[r]);
#pragma unroll
      for (int r = 0; r < 4; r++) tm = fmaxf(tm, s1[r]);
      tm = fmaxf(tm, __shfl_xor(tm, 16));
      tm = fmaxf(tm, __shfl_xor(tm, 32));
      float mnew = fmaxf(mrow[s], tm);
      float corr = __expf(mrow[s] - mnew);
      mrow[s] = mnew;
      float p0[4], p1[4], ps = 0.f;
#pragma unroll
      for (int r = 0; r < 4; r++) {
        p0[r] = __expf(s0[r] - mnew);
        p1[r] = __expf(s1[r] - mnew);
        ps += p0[r] + p1[r];
      }
      ps += __shfl_xor(ps, 16);
      ps += __shfl_xor(ps, 32);
      lrow[s] = lrow[s] * corr + ps;
#pragma unroll
      for (int c = 0; c < 4; c++) o[s][c] *= corr;

      bf16x8 pb;
#pragma unroll
      for (int r = 0; r < 4; r++) {
        pb[r]     = (__bf16)p0[r];
        pb[4 + r] = (__bf16)p1[r];
      }
#pragma unroll
      for (int c = 0; c < 4; c++)
        o[s][c] = __builtin_amdgcn_mfma_f32_16x16x32_bf16(vf[c], pb, o[s][c], 0, 0, 0);
    }
  }

#pragma unroll
  for (int s = 0; s < 4; s++) {
    float inv = 1.0f / lrow[s];
    size_t row = (size_t)b * T_ + q0 + s * 16 + ql;
    size_t baseo = row * C_ + h * DH_;
#pragma unroll
    for (int c = 0; c < 4; c++) {
      bf16x4 ov;
#pragma unroll
      for (int r = 0; r < 4; r++) ov[r] = (__bf16)(o[s][c][r] * inv);
      *(bf16x4*)(ao + baseo + c * 16 + g * 4) = ov;
    }
  }
}

extern "C" void kernel_launch(void* const* d_in, const int* in_sizes, int n_in,
                              void* d_out, int out_size, void* d_ws, size_t ws_size,
                              hipStream_t stream) {
  (void)in_sizes; (void)n_in; (void)out_size;
  const float* x  = (const float*)d_in[0];
  const float* Wq = (const float*)d_in[1];
  const float* Wk = (const float*)d_in[2];
  const float* Wv = (const float*)d_in[3];
  const float* Wo = (const float*)d_in[4];

  char* ws = (char*)d_ws;
  char* od = (char*)d_out;
  float* outp = (float*)d_out;

  // d_out (64 MiB) always hosts qb+kb (32 MiB each, exact fit); both are dead
  // before the final out-projection overwrites all of d_out.
  __bf16* qb = (__bf16*)(od);
  __bf16* kb = (__bf16*)(od + 33554432);

  const size_t NEED_B = 75628544;  // xb(32M)+vtb(32M)+wqkv(6M)+wob(2M)+tables(128K)

  if (ws_size >= NEED_B) {
    // ---- Layout B: pre-cast everything to bf16 (fast gload_lds GEMMs) ----
    __bf16* xb   = (__bf16*)(ws);                 // 32 MiB; reused as aob
    __bf16* vtb  = (__bf16*)(ws + 33554432);      // 32 MiB
    __bf16* wqkv = (__bf16*)(ws + 67108864);      // 6 MiB
    __bf16* wob  = (__bf16*)(ws + 73400320);      // 2 MiB
    float*  cosT = (float*)(ws + 75497472);
    float*  sinT = (float*)(ws + 75563008);
    __bf16* aob  = xb;  // x dead after QKV GEMM

    cast_kernel<<<dim3(16384), dim3(256), 0, stream>>>(x, xb, 4194304);
    cast_kernel<<<dim3(1024), dim3(256), 0, stream>>>(Wq, wqkv,           262144);
    cast_kernel<<<dim3(1024), dim3(256), 0, stream>>>(Wk, wqkv + 1048576, 262144);
    cast_kernel<<<dim3(1024), dim3(256), 0, stream>>>(Wv, wqkv + 2097152, 262144);
    cast_kernel<<<dim3(1024), dim3(256), 0, stream>>>(Wo, wob,            262144);
    rope_tables_kernel<<<dim3(64), dim3(256), 0, stream>>>(cosT, sinT);

    gemm_bt<0, false, false><<<dim3(3072), dim3(256), 0, stream>>>(
        xb, wqkv, wqkv + 1048576, wqkv + 2097152, qb, kb, vtb, nullptr);
    rope_apply_kernel<<<dim3(8192), dim3(256), 0, stream>>>(qb, kb, cosT, sinT);
    attn_kernel<<<dim3(B_ * NH_ * 2), dim3(256), 0, stream>>>(qb, kb, vtb, aob);
    gemm_bt<1, false, false><<<dim3(1024), dim3(256), 0, stream>>>(
        aob, wob, nullptr, nullptr, nullptr, nullptr, nullptr, outp);
  } else {
    // ---- Layout C: no pre-cast; GEMMs read f32 operands reg-staged ----
    // ws: vtb @0 (32M), aob @32M (32M); rope tables alias aob's first 128K
    // (tables consumed by rope_apply before attention writes aob).
    __bf16* vtb  = (__bf16*)(ws);
    __bf16* aob  = (__bf16*)(ws + 33554432);
    float*  cosT = (float*)(ws + 33554432);
    float*  sinT = (float*)(ws + 33619968);

    rope_tables_kernel<<<dim3(64), dim3(256), 0, stream>>>(cosT, sinT);
    gemm_bt<0, true, true><<<dim3(3072), dim3(256), 0, stream>>>(
        x, Wq, Wk, Wv, qb, kb, vtb, nullptr);
    rope_apply_kernel<<<dim3(8192), dim3(256), 0, stream>>>(qb, kb, cosT, sinT);
    attn_kernel<<<dim3(B_ * NH_ * 2), dim3(256), 0, stream>>>(qb, kb, vtb, aob);
    gemm_bt<1, false, true><<<dim3(1024), dim3(256), 0, stream>>>(
        aob, Wo, nullptr, nullptr, nullptr, nullptr, nullptr, outp);
  }
}

// Round 5
// 321.055 us; speedup vs baseline: 1.1213x; 1.1213x over previous
//
#include <hip/hip_runtime.h>
#include <hip/hip_bf16.h>
#include <stdint.h>

#define B_  32
#define T_  512
#define C_  1024
#define NH_ 16
#define DH_ 64
#define NT_ 32   // K / 32 tiles

typedef __attribute__((ext_vector_type(8))) __bf16 bf16x8;
typedef __attribute__((ext_vector_type(4))) __bf16 bf16x4;
typedef __attribute__((ext_vector_type(4))) float  f32x4;

__device__ __forceinline__ void gload_lds16(const void* g, void* lds) {
  __builtin_amdgcn_global_load_lds(
      (const __attribute__((address_space(1))) void*)(uintptr_t)g,
      (__attribute__((address_space(3))) void*)(uint32_t)(uintptr_t)lds,
      16, 0, 0);
}

// ---------------- cast f32 -> bf16 ----------------
__global__ void cast_kernel(const float* __restrict__ src, __bf16* __restrict__ dst, int n4) {
  int i = blockIdx.x * blockDim.x + threadIdx.x;
  if (i >= n4) return;
  f32x4 v = *(const f32x4*)(src + i * 4);
  bf16x4 o;
  o[0] = (__bf16)v[0]; o[1] = (__bf16)v[1]; o[2] = (__bf16)v[2]; o[3] = (__bf16)v[3];
  *(bf16x4*)(dst + i * 4) = o;
}

// ---------------- rope tables (f32) ----------------
__global__ void rope_tables_kernel(float* __restrict__ cosT, float* __restrict__ sinT) {
  int i = blockIdx.x * blockDim.x + threadIdx.x;  // T_*32
  int t = i >> 5, f = i & 31;
  float inv = powf(10000.0f, -(float)(2 * f) / 64.0f);
  float fr = (float)t * inv;
  cosT[i] = cosf(fr);
  sinT[i] = sinf(fr);
}

// ---------------- rope apply (Q scaled by 1/8) ----------------
__global__ void rope_apply_kernel(__bf16* __restrict__ q, __bf16* __restrict__ k,
                                  const float* __restrict__ cosT, const float* __restrict__ sinT) {
  int idx = blockIdx.x * blockDim.x + threadIdx.x;  // B*NH*T*8
  int chunk = idx & 7;
  int row = idx >> 3;
  int t = row & (T_ - 1);
  int base = row * DH_ + chunk * 8;
  int ci = t * 32 + chunk * 4;
  f32x4 c = *(const f32x4*)(cosT + ci);
  f32x4 s = *(const f32x4*)(sinT + ci);
  bf16x8 qv = *(const bf16x8*)(q + base);
  bf16x8 kv = *(const bf16x8*)(k + base);
  bf16x8 qo, ko;
#pragma unroll
  for (int p = 0; p < 4; p++) {
    float q0 = (float)qv[2 * p], q1 = (float)qv[2 * p + 1];
    float k0 = (float)kv[2 * p], k1 = (float)kv[2 * p + 1];
    qo[2 * p]     = (__bf16)(0.125f * (q0 * c[p] - q1 * s[p]));
    qo[2 * p + 1] = (__bf16)(0.125f * (q0 * s[p] + q1 * c[p]));
    ko[2 * p]     = (__bf16)(k0 * c[p] - k1 * s[p]);
    ko[2 * p + 1] = (__bf16)(k0 * s[p] + k1 * c[p]);
  }
  *(bf16x8*)(q + base) = qo;
  *(bf16x8*)(k + base) = ko;
}

// ---------------- 256x256 BK32 4-ring counted-vmcnt GEMM (T1+T2+T3+T4+T5) ----
// out[m,n] = sum_k A[m,k]*W[n,k]   (B^T GEMM)
// MODE 0: fused QKV (N=3072, W0/W1/W2); scatters q,k [B,NH,T,DH], vt [B,NH,DH,T]
// MODE 1: out-proj (N=1024, W0); writes f32 outp.
// LDS: As/Bs = 4 ring slots x [256][32] bf16 (64B rows). Swizzle: 16B chunk
// col ^= ((row>>1)&3)<<3, applied on BOTH pre-swizzled global source (since
// global_load_lds writes linearly) and ds_read address -> per quarter-wave
// each 4-bank group gets exactly 2 lanes = b128 floor (conflict-free).
// Schedule per phase t: stage tile t+3 -> 12 ds_read -> 32 MFMA (setprio) ->
// vmcnt(8) counted -> s_barrier -> sched_barrier. WAR: buf (t+3)&3 was last
// read at phase t-1, sealed by its barrier.
template <int MODE>
__global__ __launch_bounds__(512, 2) void gemm8(
    const __bf16* __restrict__ A,
    const __bf16* __restrict__ W0, const __bf16* __restrict__ W1, const __bf16* __restrict__ W2,
    __bf16* __restrict__ q, __bf16* __restrict__ k, __bf16* __restrict__ vt,
    float* __restrict__ outp) {
  extern __shared__ __bf16 lds[];
  __bf16* As = lds;           // [4][256][32]
  __bf16* Bs = lds + 32768;   // [4][256][32]
  const int K = C_;
  int tid = threadIdx.x;
  int lane = tid & 63, wave = tid >> 6;
  int ql = lane & 15, g = lane >> 4;
  int wr = wave >> 2, wc = wave & 3;

  // XCD-aware bijective swizzle (gridDim % 8 == 0 for both modes)
  int cpx = (int)gridDim.x >> 3;
  int bid = blockIdx.x;
  int sid = (bid & 7) * cpx + (bid >> 3);
  int bm = sid & 63;          // 64 M-tiles (16384/256)
  int bn = sid >> 6;

  const __bf16* Ag = A + (size_t)bm * 256 * K;
  const __bf16* Wg;
  if (MODE == 0) {
    int mat = bn >> 2;
    const __bf16* Wsel = (mat == 0) ? W0 : (mat == 1) ? W1 : W2;
    Wg = Wsel + (size_t)(bn & 3) * 256 * K;
  } else {
    Wg = W0 + (size_t)bn * 256 * K;
  }

  // staging coords: thread covers LDS elems [tid*8, +8) and [4096+tid*8, +8)
  int off0 = tid * 8;
  int off1 = off0 + 4096;
  int ar0 = off0 >> 5, ac0 = (off0 & 31) ^ (((ar0 >> 1) & 3) << 3);
  int ar1 = off1 >> 5, ac1 = (off1 & 31) ^ (((ar1 >> 1) & 3) << 3);
  size_t as0 = (size_t)ar0 * K + ac0;
  size_t as1 = (size_t)ar1 * K + ac1;

  // fragment ds_read offsets (within one [256][32] slot)
  int colsw = (g * 8) ^ (((ql >> 1) & 3) << 3);
  int aoff[8], boff[4];
#pragma unroll
  for (int m = 0; m < 8; m++) aoff[m] = (wr * 128 + m * 16 + ql) * 32 + colsw;
#pragma unroll
  for (int n = 0; n < 4; n++) boff[n] = (wc * 64 + n * 16 + ql) * 32 + colsw;

#define STAGE_(kt)                                   \
  {                                                  \
    int bq_ = ((kt) & 3) * 8192;                     \
    const __bf16* asrc_ = Ag + (kt) * 32;            \
    const __bf16* bsrc_ = Wg + (kt) * 32;            \
    gload_lds16(asrc_ + as0, As + bq_ + off0);       \
    gload_lds16(asrc_ + as1, As + bq_ + off1);       \
    gload_lds16(bsrc_ + as0, Bs + bq_ + off0);       \
    gload_lds16(bsrc_ + as1, Bs + bq_ + off1);       \
  }

  STAGE_(0); STAGE_(1); STAGE_(2);
  asm volatile("s_waitcnt vmcnt(8)" ::: "memory");
  __builtin_amdgcn_s_barrier();
  __builtin_amdgcn_sched_barrier(0);

  f32x4 acc[8][4] = {};
  for (int t = 0; t < NT_; ++t) {
    if (t + 3 < NT_) STAGE_(t + 3);
    int bq = (t & 3) * 8192;
    bf16x8 af[8], bfr[4];
#pragma unroll
    for (int m = 0; m < 8; m++) af[m] = *(const bf16x8*)(As + bq + aoff[m]);
#pragma unroll
    for (int n = 0; n < 4; n++) bfr[n] = *(const bf16x8*)(Bs + bq + boff[n]);
    __builtin_amdgcn_s_setprio(1);
#pragma unroll
    for (int m = 0; m < 8; m++)
#pragma unroll
      for (int n = 0; n < 4; n++)
        acc[m][n] = __builtin_amdgcn_mfma_f32_16x16x32_bf16(af[m], bfr[n], acc[m][n], 0, 0, 0);
    __builtin_amdgcn_s_setprio(0);
    if (t < NT_ - 3)       { asm volatile("s_waitcnt vmcnt(8)" ::: "memory"); }
    else if (t == NT_ - 3) { asm volatile("s_waitcnt vmcnt(4)" ::: "memory"); }
    else                   { asm volatile("s_waitcnt vmcnt(0)" ::: "memory"); }
    __builtin_amdgcn_s_barrier();
    __builtin_amdgcn_sched_barrier(0);
  }
#undef STAGE_

  int r0 = bm * 256 + wr * 128;
  int c0 = bn * 256 + wc * 64;
  if (MODE == 0) {
    int mat = c0 >> 10;  // block-uniform
#pragma unroll
    for (int m = 0; m < 8; m++) {
      int row = r0 + m * 16 + g * 4;
      int b = row >> 9, tt = row & 511;
#pragma unroll
      for (int n = 0; n < 4; n++) {
        int col = c0 + n * 16 + ql;
        int h = (col & 1023) >> 6, d = col & 63;
        if (mat == 2) {
          bf16x4 ov;
#pragma unroll
          for (int r = 0; r < 4; r++) ov[r] = (__bf16)acc[m][n][r];
          *(bf16x4*)(vt + ((size_t)(b * NH_ + h) * DH_ + d) * T_ + tt) = ov;
        } else {
          __bf16* dst = (mat == 0 ? q : k) + ((size_t)(b * NH_ + h) * T_ + tt) * DH_ + d;
#pragma unroll
          for (int r = 0; r < 4; r++) dst[r * DH_] = (__bf16)acc[m][n][r];
        }
      }
    }
  } else {
#pragma unroll
    for (int m = 0; m < 8; m++) {
      int row = r0 + m * 16 + g * 4;
#pragma unroll
      for (int r = 0; r < 4; r++)
#pragma unroll
        for (int n = 0; n < 4; n++)
          outp[(size_t)(row + r) * C_ + c0 + n * 16 + ql] = acc[m][n][r];
    }
  }
}

// ---------------- flash attention (unchanged, verified) ----------------
__global__ __launch_bounds__(256) void attn_kernel(
    const __bf16* __restrict__ qg, const __bf16* __restrict__ kg,
    const __bf16* __restrict__ vg, __bf16* __restrict__ ao) {
  int lane = threadIdx.x & 63, wave = threadIdx.x >> 6;
  int ql = lane & 15, g = lane >> 4;
  int bh = blockIdx.x >> 1;
  int q0 = (blockIdx.x & 1) * 256 + wave * 64;
  int b = bh >> 4, h = bh & 15;
  const __bf16* qp = qg + (size_t)bh * (T_ * DH_);
  const __bf16* kp = kg + (size_t)bh * (T_ * DH_);
  const __bf16* vp = vg + (size_t)bh * (T_ * DH_);  // [DH][T]

  bf16x8 qf[4][2];
#pragma unroll
  for (int s = 0; s < 4; s++)
#pragma unroll
    for (int kk = 0; kk < 2; kk++)
      qf[s][kk] = *(const bf16x8*)(qp + (q0 + s * 16 + ql) * DH_ + kk * 32 + g * 8);

  f32x4 o[4][4] = {};
  float mrow[4] = {-1e30f, -1e30f, -1e30f, -1e30f};
  float lrow[4] = {0.f, 0.f, 0.f, 0.f};

  for (int kv0 = 0; kv0 < T_; kv0 += 32) {
    bf16x8 kf[2][2], vf[4];
#pragma unroll
    for (int sub = 0; sub < 2; sub++)
#pragma unroll
      for (int kk = 0; kk < 2; kk++)
        kf[sub][kk] = *(const bf16x8*)(kp + (kv0 + sub * 16 + ql) * DH_ + kk * 32 + g * 8);
#pragma unroll
    for (int c = 0; c < 4; c++) {
      bf16x4 vlo = *(const bf16x4*)(vp + (c * 16 + ql) * T_ + kv0 + g * 4);
      bf16x4 vhi = *(const bf16x4*)(vp + (c * 16 + ql) * T_ + kv0 + 16 + g * 4);
#pragma unroll
      for (int r = 0; r < 4; r++) { vf[c][r] = vlo[r]; vf[c][4 + r] = vhi[r]; }
    }

#pragma unroll
    for (int s = 0; s < 4; s++) {
      f32x4 s0 = {0.f, 0.f, 0.f, 0.f}, s1 = {0.f, 0.f, 0.f, 0.f};
#pragma unroll
      for (int kk = 0; kk < 2; kk++) {
        s0 = __builtin_amdgcn_mfma_f32_16x16x32_bf16(kf[0][kk], qf[s][kk], s0, 0, 0, 0);
        s1 = __builtin_amdgcn_mfma_f32_16x16x32_bf16(kf[1][kk], qf[s][kk], s1, 0, 0, 0);
      }
      float tm = s0[0];
#pragma unroll
      for (int r = 1; r < 4; r++) tm = fmaxf(tm, s0[r]);
#pragma unroll
      for (int r = 0; r < 4; r++) tm = fmaxf(tm, s1[r]);
      tm = fmaxf(tm, __shfl_xor(tm, 16));
      tm = fmaxf(tm, __shfl_xor(tm, 32));
      float mnew = fmaxf(mrow[s], tm);
      float corr = __expf(mrow[s] - mnew);
      mrow[s] = mnew;
      float p0[4], p1[4], ps = 0.f;
#pragma unroll
      for (int r = 0; r < 4; r++) {
        p0[r] = __expf(s0[r] - mnew);
        p1[r] = __expf(s1[r] - mnew);
        ps += p0[r] + p1[r];
      }
      ps += __shfl_xor(ps, 16);
      ps += __shfl_xor(ps, 32);
      lrow[s] = lrow[s] * corr + ps;
#pragma unroll
      for (int c = 0; c < 4; c++) o[s][c] *= corr;

      bf16x8 pb;
#pragma unroll
      for (int r = 0; r < 4; r++) {
        pb[r]     = (__bf16)p0[r];
        pb[4 + r] = (__bf16)p1[r];
      }
#pragma unroll
      for (int c = 0; c < 4; c++)
        o[s][c] = __builtin_amdgcn_mfma_f32_16x16x32_bf16(vf[c], pb, o[s][c], 0, 0, 0);
    }
  }

#pragma unroll
  for (int s = 0; s < 4; s++) {
    float inv = 1.0f / lrow[s];
    size_t row = (size_t)b * T_ + q0 + s * 16 + ql;
    size_t baseo = row * C_ + h * DH_;
#pragma unroll
    for (int c = 0; c < 4; c++) {
      bf16x4 ov;
#pragma unroll
      for (int r = 0; r < 4; r++) ov[r] = (__bf16)(o[s][c][r] * inv);
      *(bf16x4*)(ao + baseo + c * 16 + g * 4) = ov;
    }
  }
}

extern "C" void kernel_launch(void* const* d_in, const int* in_sizes, int n_in,
                              void* d_out, int out_size, void* d_ws, size_t ws_size,
                              hipStream_t stream) {
  (void)in_sizes; (void)n_in; (void)out_size; (void)ws_size;
  const float* x  = (const float*)d_in[0];
  const float* Wq = (const float*)d_in[1];
  const float* Wk = (const float*)d_in[2];
  const float* Wv = (const float*)d_in[3];
  const float* Wo = (const float*)d_in[4];

  char* ws = (char*)d_ws;
  char* od = (char*)d_out;
  float* outp = (float*)d_out;

  // d_out hosts qb+kb (32 MiB each, exact fit); dead before out-proj overwrites.
  __bf16* qb = (__bf16*)(od);
  __bf16* kb = (__bf16*)(od + 33554432);
  // ws: xb/aob @0 (32M), vtb @32M (32M), wqkv @64M (6M), wob @70M (2M), tables @72M
  __bf16* xb   = (__bf16*)(ws);
  __bf16* vtb  = (__bf16*)(ws + 33554432);
  __bf16* wqkv = (__bf16*)(ws + 67108864);
  __bf16* wob  = (__bf16*)(ws + 73400320);
  float*  cosT = (float*)(ws + 75497472);
  float*  sinT = (float*)(ws + 75563008);
  __bf16* aob  = xb;  // x dead after QKV GEMM

  // allow 128 KiB dynamic LDS
  auto k0 = gemm8<0>; auto k1 = gemm8<1>;
  hipFuncSetAttribute((const void*)k0, hipFuncAttributeMaxDynamicSharedMemorySize, 131072);
  hipFuncSetAttribute((const void*)k1, hipFuncAttributeMaxDynamicSharedMemorySize, 131072);

  cast_kernel<<<dim3(16384), dim3(256), 0, stream>>>(x, xb, 4194304);
  cast_kernel<<<dim3(1024), dim3(256), 0, stream>>>(Wq, wqkv,           262144);
  cast_kernel<<<dim3(1024), dim3(256), 0, stream>>>(Wk, wqkv + 1048576, 262144);
  cast_kernel<<<dim3(1024), dim3(256), 0, stream>>>(Wv, wqkv + 2097152, 262144);
  cast_kernel<<<dim3(1024), dim3(256), 0, stream>>>(Wo, wob,            262144);
  rope_tables_kernel<<<dim3(64), dim3(256), 0, stream>>>(cosT, sinT);

  // QKV: M=16384, N=3072 -> 64 x 12 = 768 blocks
  gemm8<0><<<dim3(768), dim3(512), 131072, stream>>>(
      xb, wqkv, wqkv + 1048576, wqkv + 2097152, qb, kb, vtb, nullptr);
  rope_apply_kernel<<<dim3(8192), dim3(256), 0, stream>>>(qb, kb, cosT, sinT);
  attn_kernel<<<dim3(B_ * NH_ * 2), dim3(256), 0, stream>>>(qb, kb, vtb, aob);
  // out-proj: M=16384, N=1024 -> 64 x 4 = 256 blocks
  gemm8<1><<<dim3(256), dim3(512), 131072, stream>>>(
      aob, wob, nullptr, nullptr, nullptr, nullptr, nullptr, outp);
}

// Round 6
// 302.350 us; speedup vs baseline: 1.1907x; 1.0619x over previous
//
#include <hip/hip_runtime.h>
#include <hip/hip_bf16.h>
#include <stdint.h>

#define B_  32
#define T_  512
#define C_  1024
#define NH_ 16
#define DH_ 64
#define NT_ 32   // K / 32 tiles

typedef __attribute__((ext_vector_type(8))) __bf16 bf16x8;
typedef __attribute__((ext_vector_type(4))) __bf16 bf16x4;
typedef __attribute__((ext_vector_type(4))) float  f32x4;

__device__ __forceinline__ void gload_lds16(const void* g, void* lds) {
  __builtin_amdgcn_global_load_lds(
      (const __attribute__((address_space(1))) void*)(uintptr_t)g,
      (__attribute__((address_space(3))) void*)(uint32_t)(uintptr_t)lds,
      16, 0, 0);
}

// ---------------- cast f32 -> bf16 ----------------
__global__ void cast_kernel(const float* __restrict__ src, __bf16* __restrict__ dst, int n4) {
  int i = blockIdx.x * blockDim.x + threadIdx.x;
  if (i >= n4) return;
  f32x4 v = *(const f32x4*)(src + i * 4);
  bf16x4 o;
  o[0] = (__bf16)v[0]; o[1] = (__bf16)v[1]; o[2] = (__bf16)v[2]; o[3] = (__bf16)v[3];
  *(bf16x4*)(dst + i * 4) = o;
}

// ---------------- rope tables (f32) ----------------
__global__ void rope_tables_kernel(float* __restrict__ cosT, float* __restrict__ sinT) {
  int i = blockIdx.x * blockDim.x + threadIdx.x;  // T_*32
  int t = i >> 5, f = i & 31;
  float inv = powf(10000.0f, -(float)(2 * f) / 64.0f);
  float fr = (float)t * inv;
  cosT[i] = cosf(fr);
  sinT[i] = sinf(fr);
}

// ---------------- rope apply (Q scaled by 1/8) ----------------
__global__ void rope_apply_kernel(__bf16* __restrict__ q, __bf16* __restrict__ k,
                                  const float* __restrict__ cosT, const float* __restrict__ sinT) {
  int idx = blockIdx.x * blockDim.x + threadIdx.x;  // B*NH*T*8
  int chunk = idx & 7;
  int row = idx >> 3;
  int t = row & (T_ - 1);
  int base = row * DH_ + chunk * 8;
  int ci = t * 32 + chunk * 4;
  f32x4 c = *(const f32x4*)(cosT + ci);
  f32x4 s = *(const f32x4*)(sinT + ci);
  bf16x8 qv = *(const bf16x8*)(q + base);
  bf16x8 kv = *(const bf16x8*)(k + base);
  bf16x8 qo, ko;
#pragma unroll
  for (int p = 0; p < 4; p++) {
    float q0 = (float)qv[2 * p], q1 = (float)qv[2 * p + 1];
    float k0 = (float)kv[2 * p], k1 = (float)kv[2 * p + 1];
    qo[2 * p]     = (__bf16)(0.125f * (q0 * c[p] - q1 * s[p]));
    qo[2 * p + 1] = (__bf16)(0.125f * (q0 * s[p] + q1 * c[p]));
    ko[2 * p]     = (__bf16)(k0 * c[p] - k1 * s[p]);
    ko[2 * p + 1] = (__bf16)(k0 * s[p] + k1 * c[p]);
  }
  *(bf16x8*)(q + base) = qo;
  *(bf16x8*)(k + base) = ko;
}

// ---------------- 256x256 BK32 4-ring counted-vmcnt GEMM ----------------
// out[m,n] = sum_k A[m,k]*W[n,k]   (B^T GEMM)
// MODE 0: fused QKV (N=3072); MODE 1: out-proj (N=1024, f32 out).
// L2-aware XCD ownership: each XCD owns 16 bm x (NBN/2) bn, bn-fastest
// within bm -> per-XCD hot set = NBN/2 W-tiles (3MB) + 1 active A-tile.
// LDS swizzle (chunk-XOR col ^= ((row>>1)&3)<<3 on both pre-swizzled global
// source and ds_read addr) -> 0 bank conflicts (verified round 5).
template <int MODE>
__global__ __launch_bounds__(512, 2) void gemm8(
    const __bf16* __restrict__ A,
    const __bf16* __restrict__ W0, const __bf16* __restrict__ W1, const __bf16* __restrict__ W2,
    __bf16* __restrict__ q, __bf16* __restrict__ k, __bf16* __restrict__ vt,
    float* __restrict__ outp) {
  extern __shared__ __bf16 lds[];
  __bf16* As = lds;           // [4][256][32]
  __bf16* Bs = lds + 32768;   // [4][256][32]
  const int K = C_;
  int tid = threadIdx.x;
  int lane = tid & 63, wave = tid >> 6;
  int ql = lane & 15, g = lane >> 4;
  int wr = wave >> 2, wc = wave & 3;

  // XCD-aware L2-blocked mapping (bijective; gridDim % 8 == 0)
  constexpr int BNH = (MODE == 0) ? 6 : 2;   // bn per XCD
  int bid = blockIdx.x;
  int xcd = bid & 7, local = bid >> 3;
  int bm = (xcd >> 1) * 16 + local / BNH;
  int bn = (xcd & 1) * BNH + local % BNH;

  const __bf16* Ag = A + (size_t)bm * 256 * K;
  const __bf16* Wg;
  if (MODE == 0) {
    int mat = bn >> 2;
    const __bf16* Wsel = (mat == 0) ? W0 : (mat == 1) ? W1 : W2;
    Wg = Wsel + (size_t)(bn & 3) * 256 * K;
  } else {
    Wg = W0 + (size_t)bn * 256 * K;
  }

  // staging coords: thread covers LDS elems [tid*8, +8) and [4096+tid*8, +8)
  int off0 = tid * 8;
  int off1 = off0 + 4096;
  int ar0 = off0 >> 5, ac0 = (off0 & 31) ^ (((ar0 >> 1) & 3) << 3);
  int ar1 = off1 >> 5, ac1 = (off1 & 31) ^ (((ar1 >> 1) & 3) << 3);
  size_t as0 = (size_t)ar0 * K + ac0;
  size_t as1 = (size_t)ar1 * K + ac1;

  // fragment ds_read offsets (within one [256][32] slot)
  int colsw = (g * 8) ^ (((ql >> 1) & 3) << 3);
  int aoff[8], boff[4];
#pragma unroll
  for (int m = 0; m < 8; m++) aoff[m] = (wr * 128 + m * 16 + ql) * 32 + colsw;
#pragma unroll
  for (int n = 0; n < 4; n++) boff[n] = (wc * 64 + n * 16 + ql) * 32 + colsw;

#define STAGE_(kt)                                   \
  {                                                  \
    int bq_ = ((kt) & 3) * 8192;                     \
    const __bf16* asrc_ = Ag + (kt) * 32;            \
    const __bf16* bsrc_ = Wg + (kt) * 32;            \
    gload_lds16(asrc_ + as0, As + bq_ + off0);       \
    gload_lds16(asrc_ + as1, As + bq_ + off1);       \
    gload_lds16(bsrc_ + as0, Bs + bq_ + off0);       \
    gload_lds16(bsrc_ + as1, Bs + bq_ + off1);       \
  }

  STAGE_(0); STAGE_(1); STAGE_(2);
  asm volatile("s_waitcnt vmcnt(8)" ::: "memory");
  __builtin_amdgcn_s_barrier();
  __builtin_amdgcn_sched_barrier(0);

  f32x4 acc[8][4] = {};
  for (int t = 0; t < NT_; ++t) {
    if (t + 3 < NT_) STAGE_(t + 3);
    int bq = (t & 3) * 8192;
    bf16x8 af[8], bfr[4];
#pragma unroll
    for (int m = 0; m < 8; m++) af[m] = *(const bf16x8*)(As + bq + aoff[m]);
#pragma unroll
    for (int n = 0; n < 4; n++) bfr[n] = *(const bf16x8*)(Bs + bq + boff[n]);
    __builtin_amdgcn_s_setprio(1);
#pragma unroll
    for (int m = 0; m < 8; m++)
#pragma unroll
      for (int n = 0; n < 4; n++)
        acc[m][n] = __builtin_amdgcn_mfma_f32_16x16x32_bf16(af[m], bfr[n], acc[m][n], 0, 0, 0);
    __builtin_amdgcn_s_setprio(0);
    if (t < NT_ - 3)       { asm volatile("s_waitcnt vmcnt(8)" ::: "memory"); }
    else if (t == NT_ - 3) { asm volatile("s_waitcnt vmcnt(4)" ::: "memory"); }
    else                   { asm volatile("s_waitcnt vmcnt(0)" ::: "memory"); }
    __builtin_amdgcn_s_barrier();
    __builtin_amdgcn_sched_barrier(0);
  }
#undef STAGE_

  int r0 = bm * 256 + wr * 128;
  int c0 = bn * 256 + wc * 64;
  if (MODE == 0) {
    int mat = c0 >> 10;  // block-uniform
#pragma unroll
    for (int m = 0; m < 8; m++) {
      int row = r0 + m * 16 + g * 4;
      int b = row >> 9, tt = row & 511;
#pragma unroll
      for (int n = 0; n < 4; n++) {
        int col = c0 + n * 16 + ql;
        int h = (col & 1023) >> 6, d = col & 63;
        if (mat == 2) {
          bf16x4 ov;
#pragma unroll
          for (int r = 0; r < 4; r++) ov[r] = (__bf16)acc[m][n][r];
          *(bf16x4*)(vt + ((size_t)(b * NH_ + h) * DH_ + d) * T_ + tt) = ov;
        } else {
          __bf16* dst = (mat == 0 ? q : k) + ((size_t)(b * NH_ + h) * T_ + tt) * DH_ + d;
#pragma unroll
          for (int r = 0; r < 4; r++) dst[r * DH_] = (__bf16)acc[m][n][r];
        }
      }
    }
  } else {
#pragma unroll
    for (int m = 0; m < 8; m++) {
      int row = r0 + m * 16 + g * 4;
#pragma unroll
      for (int r = 0; r < 4; r++)
#pragma unroll
        for (int n = 0; n < 4; n++)
          outp[(size_t)(row + r) * C_ + c0 + n * 16 + ql] = acc[m][n][r];
    }
  }
}

// ---------------- flash attention: reg double-buffer prefetch + defer-max ----
// grid = B*NH*2 blocks, 256 threads (4 waves); each wave owns 64 q rows.
// Fragment math identical to round 5 (verified). New: K/V for tile t+1
// loaded before processing tile t (latency hides under softmax+MFMA);
// T13 defer-max THR=8 (skip O/l rescale when __all(tm <= m+8), exact);
// T5 setprio around MFMA clusters.
__global__ __launch_bounds__(256) void attn_kernel(
    const __bf16* __restrict__ qg, const __bf16* __restrict__ kg,
    const __bf16* __restrict__ vg, __bf16* __restrict__ ao) {
  int lane = threadIdx.x & 63, wave = threadIdx.x >> 6;
  int ql = lane & 15, g = lane >> 4;
  int bh = blockIdx.x >> 1;
  int q0 = (blockIdx.x & 1) * 256 + wave * 64;
  int b = bh >> 4, h = bh & 15;
  const __bf16* qp = qg + (size_t)bh * (T_ * DH_);
  const __bf16* kp = kg + (size_t)bh * (T_ * DH_);
  const __bf16* vp = vg + (size_t)bh * (T_ * DH_);  // [DH][T]

  bf16x8 qf[4][2];
#pragma unroll
  for (int s = 0; s < 4; s++)
#pragma unroll
    for (int kk = 0; kk < 2; kk++)
      qf[s][kk] = *(const bf16x8*)(qp + (q0 + s * 16 + ql) * DH_ + kk * 32 + g * 8);

  f32x4 o[4][4] = {};
  float mrow[4] = {-1e30f, -1e30f, -1e30f, -1e30f};
  float lrow[4] = {0.f, 0.f, 0.f, 0.f};

  bf16x8 kfA[2][2], vfA[4], kfB[2][2], vfB[4];

  auto loadT = [&](bf16x8 (&KF)[2][2], bf16x8 (&VF)[4], int kv0) {
#pragma unroll
    for (int sub = 0; sub < 2; sub++)
#pragma unroll
      for (int kk = 0; kk < 2; kk++)
        KF[sub][kk] = *(const bf16x8*)(kp + (kv0 + sub * 16 + ql) * DH_ + kk * 32 + g * 8);
#pragma unroll
    for (int c = 0; c < 4; c++) {
      bf16x4 vlo = *(const bf16x4*)(vp + (c * 16 + ql) * T_ + kv0 + g * 4);
      bf16x4 vhi = *(const bf16x4*)(vp + (c * 16 + ql) * T_ + kv0 + 16 + g * 4);
#pragma unroll
      for (int r = 0; r < 4; r++) { VF[c][r] = vlo[r]; VF[c][4 + r] = vhi[r]; }
    }
  };

  auto procT = [&](bf16x8 (&KF)[2][2], bf16x8 (&VF)[4]) {
#pragma unroll
    for (int s = 0; s < 4; s++) {
      f32x4 s0 = {0.f, 0.f, 0.f, 0.f}, s1 = {0.f, 0.f, 0.f, 0.f};
      __builtin_amdgcn_s_setprio(1);
#pragma unroll
      for (int kk = 0; kk < 2; kk++) {
        s0 = __builtin_amdgcn_mfma_f32_16x16x32_bf16(KF[0][kk], qf[s][kk], s0, 0, 0, 0);
        s1 = __builtin_amdgcn_mfma_f32_16x16x32_bf16(KF[1][kk], qf[s][kk], s1, 0, 0, 0);
      }
      __builtin_amdgcn_s_setprio(0);
      float tm = s0[0];
#pragma unroll
      for (int r = 1; r < 4; r++) tm = fmaxf(tm, s0[r]);
#pragma unroll
      for (int r = 0; r < 4; r++) tm = fmaxf(tm, s1[r]);
      tm = fmaxf(tm, __shfl_xor(tm, 16));
      tm = fmaxf(tm, __shfl_xor(tm, 32));
      // defer-max: rescale only if some column's max grew by > 8
      if (!__all(tm <= mrow[s] + 8.0f)) {
        float mnew = fmaxf(mrow[s], tm);
        float corr = __expf(mrow[s] - mnew);
        mrow[s] = mnew;
        lrow[s] *= corr;
#pragma unroll
        for (int c = 0; c < 4; c++) o[s][c] *= corr;
      }
      float p0[4], p1[4], ps = 0.f;
#pragma unroll
      for (int r = 0; r < 4; r++) {
        p0[r] = __expf(s0[r] - mrow[s]);
        p1[r] = __expf(s1[r] - mrow[s]);
        ps += p0[r] + p1[r];
      }
      ps += __shfl_xor(ps, 16);
      ps += __shfl_xor(ps, 32);
      lrow[s] += ps;
      bf16x8 pb;
#pragma unroll
      for (int r = 0; r < 4; r++) {
        pb[r]     = (__bf16)p0[r];
        pb[4 + r] = (__bf16)p1[r];
      }
      __builtin_amdgcn_s_setprio(1);
#pragma unroll
      for (int c = 0; c < 4; c++)
        o[s][c] = __builtin_amdgcn_mfma_f32_16x16x32_bf16(VF[c], pb, o[s][c], 0, 0, 0);
      __builtin_amdgcn_s_setprio(0);
    }
  };

  loadT(kfA, vfA, 0);
  for (int kv0 = 0; kv0 < T_; kv0 += 64) {
    loadT(kfB, vfB, kv0 + 32);
    procT(kfA, vfA);
    if (kv0 + 64 < T_) loadT(kfA, vfA, kv0 + 64);
    procT(kfB, vfB);
  }

#pragma unroll
  for (int s = 0; s < 4; s++) {
    float inv = 1.0f / lrow[s];
    size_t row = (size_t)b * T_ + q0 + s * 16 + ql;
    size_t baseo = row * C_ + h * DH_;
#pragma unroll
    for (int c = 0; c < 4; c++) {
      bf16x4 ov;
#pragma unroll
      for (int r = 0; r < 4; r++) ov[r] = (__bf16)(o[s][c][r] * inv);
      *(bf16x4*)(ao + baseo + c * 16 + g * 4) = ov;
    }
  }
}

extern "C" void kernel_launch(void* const* d_in, const int* in_sizes, int n_in,
                              void* d_out, int out_size, void* d_ws, size_t ws_size,
                              hipStream_t stream) {
  (void)in_sizes; (void)n_in; (void)out_size; (void)ws_size;
  const float* x  = (const float*)d_in[0];
  const float* Wq = (const float*)d_in[1];
  const float* Wk = (const float*)d_in[2];
  const float* Wv = (const float*)d_in[3];
  const float* Wo = (const float*)d_in[4];

  char* ws = (char*)d_ws;
  char* od = (char*)d_out;
  float* outp = (float*)d_out;

  // d_out hosts qb+kb (32 MiB each, exact fit); dead before out-proj overwrites.
  __bf16* qb = (__bf16*)(od);
  __bf16* kb = (__bf16*)(od + 33554432);
  // ws: xb/aob @0 (32M), vtb @32M (32M), wqkv @64M (6M), wob @70M (2M), tables @72M
  __bf16* xb   = (__bf16*)(ws);
  __bf16* vtb  = (__bf16*)(ws + 33554432);
  __bf16* wqkv = (__bf16*)(ws + 67108864);
  __bf16* wob  = (__bf16*)(ws + 73400320);
  float*  cosT = (float*)(ws + 75497472);
  float*  sinT = (float*)(ws + 75563008);
  __bf16* aob  = xb;  // x dead after QKV GEMM

  // allow 128 KiB dynamic LDS
  auto k0 = gemm8<0>; auto k1 = gemm8<1>;
  hipFuncSetAttribute((const void*)k0, hipFuncAttributeMaxDynamicSharedMemorySize, 131072);
  hipFuncSetAttribute((const void*)k1, hipFuncAttributeMaxDynamicSharedMemorySize, 131072);

  cast_kernel<<<dim3(16384), dim3(256), 0, stream>>>(x, xb, 4194304);
  cast_kernel<<<dim3(1024), dim3(256), 0, stream>>>(Wq, wqkv,           262144);
  cast_kernel<<<dim3(1024), dim3(256), 0, stream>>>(Wk, wqkv + 1048576, 262144);
  cast_kernel<<<dim3(1024), dim3(256), 0, stream>>>(Wv, wqkv + 2097152, 262144);
  cast_kernel<<<dim3(1024), dim3(256), 0, stream>>>(Wo, wob,            262144);
  rope_tables_kernel<<<dim3(64), dim3(256), 0, stream>>>(cosT, sinT);

  // QKV: M=16384, N=3072 -> 64 x 12 = 768 blocks
  gemm8<0><<<dim3(768), dim3(512), 131072, stream>>>(
      xb, wqkv, wqkv + 1048576, wqkv + 2097152, qb, kb, vtb, nullptr);
  rope_apply_kernel<<<dim3(8192), dim3(256), 0, stream>>>(qb, kb, cosT, sinT);
  attn_kernel<<<dim3(B_ * NH_ * 2), dim3(256), 0, stream>>>(qb, kb, vtb, aob);
  // out-proj: M=16384, N=1024 -> 64 x 4 = 256 blocks
  gemm8<1><<<dim3(256), dim3(512), 131072, stream>>>(
      aob, wob, nullptr, nullptr, nullptr, nullptr, nullptr, outp);
}